// Round 1
// baseline (21262.234 us; speedup 1.0000x reference)
//
#include <hip/hip_runtime.h>
#include <hip/hip_bf16.h>
#include <stdint.h>

typedef __bf16 bf16;
typedef __bf16 bf16x8 __attribute__((ext_vector_type(8)));
typedef __bf16 bf16x4 __attribute__((ext_vector_type(4)));
typedef float f32x16 __attribute__((ext_vector_type(16)));

#define LL 1024
#define BB 64
#define HH 512
#define NA 24
#define NB 8

// ---------------- ws layout (bytes) ----------------
#define OFF_X      ((size_t)0)           // [LL][BB][HH] bf16   67,108,864
#define OFF_WGSEL  ((size_t)67108864)    // [1536][512] bf16     1,572,864
#define OFF_WCIH   ((size_t)68681728)    // [512][512]  bf16       524,288
#define OFF_HBUF   ((size_t)69206016)    // [2][64][512] bf16      131,072
#define OFF_A2     ((size_t)69337088)    // [2][64][512] bf16      131,072
#define OFF_ZBUF   ((size_t)69468160)    // [2][2][64][512] f32  1,048,576
#define OFF_CTR    ((size_t)70516736)    // 256 B counters

static __device__ __forceinline__ float sigm(float x) {
  return 1.0f / (1.0f + __expf(-x));
}
static __device__ __forceinline__ float tanhx(float x) {
  x = fminf(15.0f, fmaxf(-15.0f, x));
  float e = __expf(2.0f * x);
  return (e - 1.0f) / (e + 1.0f);
}

// acquire-wait: poll device-scope counter, then fence (inv L1/L2) before block proceeds
static __device__ __forceinline__ void wgwait(unsigned* c, unsigned tgt) {
  if (threadIdx.x == 0) {
    while (__hip_atomic_load(c, __ATOMIC_RELAXED, __HIP_MEMORY_SCOPE_AGENT) < tgt) {}
    __threadfence();
  }
  __syncthreads();
}
// release-signal: barrier drains all waves' stores (vmcnt), fence writes back L2, then count
static __device__ __forceinline__ void wgsignal(unsigned* c) {
  __syncthreads();
  if (threadIdx.x == 0) {
    __threadfence();
    __hip_atomic_fetch_add(c, 1u, __ATOMIC_RELAXED, __HIP_MEMORY_SCOPE_AGENT);
  }
}

// swizzled LDS b-frag read: row i (weight out-col), 8 consecutive k; byte ^= (i&7)<<4 (G4)
static __device__ __forceinline__ bf16x8 ldsfrag(const bf16* w, int i, int k) {
  unsigned byte = ((unsigned)i << 10) + ((unsigned)k << 1);
  byte ^= ((unsigned)(i & 7) << 4);
  return *(const bf16x8*)((const char*)w + byte);
}

__global__ __launch_bounds__(256) void k_cvt_x(const float* __restrict__ in,
                                               bf16* __restrict__ o) {
  size_t i = ((size_t)blockIdx.x * 256 + threadIdx.x) * 4;
  float4 f = *(const float4*)(in + i);
  bf16x4 v;
  v[0] = (bf16)f.x; v[1] = (bf16)f.y; v[2] = (bf16)f.z; v[3] = (bf16)f.w;
  *(bf16x4*)(o + i) = v;
}

// pack W_gih rows {rl:0..511, zl:1024..1535, z:2048..2559} -> wgsel[1536][512] bf16,
// and W_cih -> wcb[512][512] bf16
__global__ __launch_bounds__(256) void k_cvt_w(const float* __restrict__ wgih,
                                               const float* __restrict__ wcf,
                                               bf16* __restrict__ wgsel,
                                               bf16* __restrict__ wcb) {
  int i = blockIdx.x * 256 + threadIdx.x;
  const int NQ1 = (1536 * 512) / 4;
  const float* s;
  bf16* d;
  if (i < NQ1) {
    int e = i * 4;
    int p = e >> 9, k = e & 511;
    int shift = (p < 512) ? 0 : ((p < 1024) ? 512 : 1024);
    s = wgih + (size_t)(p + shift) * 512 + k;
    d = wgsel + (size_t)p * 512 + k;
  } else {
    int e = (i - NQ1) * 4;
    int n = e >> 9, k = e & 511;
    s = wcf + (size_t)n * 512 + k;
    d = wcb + (size_t)n * 512 + k;
  }
  float4 f = *(const float4*)s;
  bf16x4 v;
  v[0] = (bf16)f.x; v[1] = (bf16)f.y; v[2] = (bf16)f.z; v[3] = (bf16)f.w;
  *(bf16x4*)d = v;
}

// Persistent recurrence kernel. 32 WGs x 256 thr (4 waves, one 32x32 MFMA tile each).
// WGs 0..7: rl cols, 8..15: zl, 16..23: z (each 64 gate-cols), 24..31: cell cols.
__global__ __launch_bounds__(256) void k_main(
    const bf16* __restrict__ xbf, const bf16* __restrict__ wgsel,
    const bf16* __restrict__ wcb, const float* __restrict__ wglhh,
    const float* __restrict__ wclhh, const float* __restrict__ bg,
    const float* __restrict__ bc, float* __restrict__ out,
    bf16* __restrict__ hbuf, bf16* __restrict__ a2buf,
    float* __restrict__ zbuf, unsigned* __restrict__ ctrs) {
  __shared__ bf16 wlds[64 * 512];  // 64 KB: this WG's recurrent-weight slice (swizzled)
  const int wg = blockIdx.x;
  const int tid = threadIdx.x;
  const int lane = tid & 63;
  const int wave = tid >> 6;
  unsigned* a_done = ctrs;        // +24 per step (gates published)
  unsigned* b_done = ctrs + 32;   // +8 per step (h published), separate line

  const bool isA = (wg < NA);

  // ---- load this WG's recurrent weights into LDS (fp32 global -> bf16, swizzled) ----
  {
    const float* wsrc;
    if (isA) {
      int shift = (wg < 8) ? 0 : ((wg < 16) ? 512 : 1024);
      wsrc = wglhh + (size_t)(wg * 64 + shift) * HH;
    } else {
      wsrc = wclhh + (size_t)((wg - NA) * 64) * HH;
    }
    for (int u = tid; u < 64 * 64; u += 256) {
      int i = u >> 6, k8 = (u & 63) << 3;
      const float* s = wsrc + i * HH + k8;
      bf16x8 v;
      #pragma unroll
      for (int j = 0; j < 8; ++j) v[j] = (bf16)s[j];
      unsigned byte = ((unsigned)i << 10) + ((unsigned)k8 << 1);
      byte ^= ((unsigned)(i & 7) << 4);
      *(bf16x8*)((char*)wlds + byte) = v;
    }
    __syncthreads();
  }

  const int m0 = (wave & 1) * 32;      // row tile
  const int nt = wave >> 1;            // col sub-tile (0/1)
  const int kq = (lane >> 5) * 8;      // k-half offset within K=16 step
  const int lr = lane & 31;
  const int mrow = m0 + 4 * (lane >> 5);  // C-layout row base

  if (isA) {
    const int p = wg * 64 + nt * 32 + lr;   // packed gate col (0..1535), b-operand row
    const int gsel = wg >> 3;               // 0 rl, 1 zl, 2 z
    const int shift = gsel * 512;           // packed -> actual gate row offset
    const float bias = bg[p + shift];
    f32x16 acc;

    // x-part of step 0 (no dependence)
    #pragma unroll
    for (int r = 0; r < 16; ++r) acc[r] = bias;
    #pragma unroll 4
    for (int kk = 0; kk < 32; ++kk) {
      int k = kk * 16 + kq;
      bf16x8 a = *(const bf16x8*)(xbf + (size_t)(m0 + lr) * HH + k);
      bf16x8 b = *(const bf16x8*)(wgsel + (size_t)p * HH + k);
      acc = __builtin_amdgcn_mfma_f32_32x32x16_bf16(a, b, acc, 0, 0, 0);
    }

    for (int t = 0; t < LL; ++t) {
      if (t > 0) {
        wgwait(b_done, (unsigned)(NB * t));   // h(t-1) published
        const bf16* ha = hbuf + (size_t)((t + 1) & 1) * (BB * HH);
        #pragma unroll 4
        for (int kk = 0; kk < 32; ++kk) {
          int k = kk * 16 + kq;
          bf16x8 a = *(const bf16x8*)(ha + (size_t)(m0 + lr) * HH + k);
          bf16x8 b = ldsfrag(wlds, nt * 32 + lr, k);
          acc = __builtin_amdgcn_mfma_f32_32x32x16_bf16(a, b, acc, 0, 0, 0);
        }
      }
      const int par = t & 1;
      if (gsel == 0) {
        // rl: publish a2 = sigmoid(g) * h_prev (fp32 h_prev from d_out for accuracy)
        bf16* a2 = a2buf + (size_t)par * (BB * HH);
        #pragma unroll
        for (int r = 0; r < 16; ++r) {
          int m = mrow + (r & 3) + 8 * (r >> 2);
          float g = sigm(acc[r]);
          float hp = (t > 0) ? out[(size_t)m * (LL * HH) + (size_t)(t - 1) * HH + p] : 0.0f;
          a2[m * HH + p] = (bf16)(g * hp);
        }
      } else {
        float* zb = zbuf + (size_t)(par * 2 + (gsel - 1)) * (BB * HH);
        const int n = p - shift;
        #pragma unroll
        for (int r = 0; r < 16; ++r) {
          int m = mrow + (r & 3) + 8 * (r >> 2);
          zb[m * HH + n] = sigm(acc[r]);
        }
      }
      wgsignal(a_done);
      if (t + 1 < LL) {  // x-part of next step, hidden behind B's phase
        #pragma unroll
        for (int r = 0; r < 16; ++r) acc[r] = bias;
        const bf16* xa = xbf + (size_t)(t + 1) * (BB * HH);
        #pragma unroll 4
        for (int kk = 0; kk < 32; ++kk) {
          int k = kk * 16 + kq;
          bf16x8 a = *(const bf16x8*)(xa + (size_t)(m0 + lr) * HH + k);
          bf16x8 b = *(const bf16x8*)(wgsel + (size_t)p * HH + k);
          acc = __builtin_amdgcn_mfma_f32_32x32x16_bf16(a, b, acc, 0, 0, 0);
        }
      }
    }
  } else {
    const int n = (wg - NA) * 64 + nt * 32 + lr;  // hidden col, b-operand row
    const float bias = bc[n];
    f32x16 acc;

    // xc-part of step 0
    #pragma unroll
    for (int r = 0; r < 16; ++r) acc[r] = bias;
    #pragma unroll 4
    for (int kk = 0; kk < 32; ++kk) {
      int k = kk * 16 + kq;
      bf16x8 a = *(const bf16x8*)(xbf + (size_t)(m0 + lr) * HH + k);
      bf16x8 b = *(const bf16x8*)(wcb + (size_t)n * HH + k);
      acc = __builtin_amdgcn_mfma_f32_32x32x16_bf16(a, b, acc, 0, 0, 0);
    }

    for (int t = 0; t < LL; ++t) {
      wgwait(a_done, (unsigned)(NA * (t + 1)));  // all gates of step t published
      const int par = t & 1;
      if (t > 0) {  // a2 == 0 at t=0
        const bf16* aa = a2buf + (size_t)par * (BB * HH);
        #pragma unroll 4
        for (int kk = 0; kk < 32; ++kk) {
          int k = kk * 16 + kq;
          bf16x8 a = *(const bf16x8*)(aa + (size_t)(m0 + lr) * HH + k);
          bf16x8 b = ldsfrag(wlds, nt * 32 + lr, k);
          acc = __builtin_amdgcn_mfma_f32_32x32x16_bf16(a, b, acc, 0, 0, 0);
        }
      }
      const float* zl = zbuf + (size_t)(par * 2 + 0) * (BB * HH);
      const float* zz = zbuf + (size_t)(par * 2 + 1) * (BB * HH);
      bf16* hb = hbuf + (size_t)par * (BB * HH);
      #pragma unroll
      for (int r = 0; r < 16; ++r) {
        int m = mrow + (r & 3) + 8 * (r >> 2);
        float cell = tanhx(acc[r]);
        float zlv = zl[m * HH + n];
        float zv = zz[m * HH + n];
        float hp = (t > 0) ? out[(size_t)m * (LL * HH) + (size_t)(t - 1) * HH + n] : 0.0f;
        float h = zlv * hp + zv * cell;
        out[(size_t)m * (LL * HH) + (size_t)t * HH + n] = h;  // fp32 h (also next-step h_prev source)
        hb[m * HH + n] = (bf16)h;                             // bf16 h for MFMA consumers
      }
      wgsignal(b_done);
      if (t + 1 < LL) {  // xc-part of next step, hidden behind A's phase
        #pragma unroll
        for (int r = 0; r < 16; ++r) acc[r] = bias;
        const bf16* xa = xbf + (size_t)(t + 1) * (BB * HH);
        #pragma unroll 4
        for (int kk = 0; kk < 32; ++kk) {
          int k = kk * 16 + kq;
          bf16x8 a = *(const bf16x8*)(xa + (size_t)(m0 + lr) * HH + k);
          bf16x8 b = *(const bf16x8*)(wcb + (size_t)n * HH + k);
          acc = __builtin_amdgcn_mfma_f32_32x32x16_bf16(a, b, acc, 0, 0, 0);
        }
      }
    }
  }
}

extern "C" void kernel_launch(void* const* d_in, const int* in_sizes, int n_in,
                              void* d_out, int out_size, void* d_ws, size_t ws_size,
                              hipStream_t stream) {
  (void)in_sizes; (void)n_in; (void)out_size; (void)ws_size;
  const float* x     = (const float*)d_in[0];
  // d_in[1] = indexes (chain tree, unused)
  const float* wgih  = (const float*)d_in[2];
  const float* bg    = (const float*)d_in[3];
  const float* wglhh = (const float*)d_in[4];
  // d_in[5] = W_grhh unused (right child == 0)
  const float* wcihf = (const float*)d_in[6];
  const float* bc    = (const float*)d_in[7];
  const float* wclhh = (const float*)d_in[8];
  // d_in[9] = W_crhh unused
  float* out = (float*)d_out;

  char* ws = (char*)d_ws;
  bf16* xbf     = (bf16*)(ws + OFF_X);
  bf16* wgsel   = (bf16*)(ws + OFF_WGSEL);
  bf16* wcb     = (bf16*)(ws + OFF_WCIH);
  bf16* hbuf    = (bf16*)(ws + OFF_HBUF);
  bf16* a2buf   = (bf16*)(ws + OFF_A2);
  float* zbuf   = (float*)(ws + OFF_ZBUF);
  unsigned* ctr = (unsigned*)(ws + OFF_CTR);

  // counters must start at 0 every call (ws not re-poisoned between replays)
  hipMemsetAsync(ctr, 0, 256, stream);
  // output_t tail is zeros per reference
  hipMemsetAsync(out + (size_t)BB * LL * HH, 0, (size_t)BB * HH * sizeof(float), stream);

  k_cvt_x<<<dim3(32768), dim3(256), 0, stream>>>(x, xbf);
  k_cvt_w<<<dim3(1024), dim3(256), 0, stream>>>(wgih, wcihf, wgsel, wcb);
  k_main<<<dim3(NA + NB), dim3(256), 0, stream>>>(xbf, wgsel, wcb, wglhh, wclhh,
                                                  bg, bc, out, hbuf, a2buf, zbuf, ctr);
}